// Round 12
// baseline (248.070 us; speedup 1.0000x reference)
//
#include <hip/hip_runtime.h>
#include <hip/hip_bf16.h>

#define B_ 32
#define T_ 1024
#define H_ 16
#define D_ 64
#define M_ (B_*T_)      // 32768 rows
#define N_ (H_*D_*2)    // 2048 cols
#define K_ 1024
#define CHUNKS 16
#define CLEN (T_/CHUNKS)   // 64

typedef __bf16 bf16x8 __attribute__((ext_vector_type(8)));
typedef float  f32x4  __attribute__((ext_vector_type(4)));
typedef unsigned short u16x8 __attribute__((ext_vector_type(8)));

__device__ __forceinline__ float bf2f(unsigned short u){
  union{ float f; unsigned int i; } c; c.i = ((unsigned int)u) << 16; return c.f;
}
__device__ __forceinline__ unsigned short f2bf(float f){
  union{ float f; unsigned int i; } c; c.f = f;
  unsigned int r = (c.i + 0x7FFFu + ((c.i >> 16) & 1u)) >> 16;   // RNE
  return (unsigned short)r;
}
__device__ __forceinline__ float silu(float x){ return x / (1.0f + __expf(-x)); }
__device__ __forceinline__ float frcp(float x){
  float r; asm("v_rcp_f32 %0, %1" : "=v"(r) : "v"(x)); return r;
}

__device__ __forceinline__ void gload16(const void* g, void* l){
  __builtin_amdgcn_global_load_lds(
      (const __attribute__((address_space(1))) void*)g,
      (__attribute__((address_space(3))) void*)l, 16, 0, 0);
}

#define BAR()   __builtin_amdgcn_s_barrier()
#define LGKM0() asm volatile("s_waitcnt lgkmcnt(0)" ::: "memory")
#define VM4()   asm volatile("s_waitcnt vmcnt(4)" ::: "memory")
#define VM0()   asm volatile("s_waitcnt vmcnt(0)" ::: "memory")

// ---- K0: fused x->bf16 (blocks 0..2047) + W transpose (blocks 2048+) ---
__global__ __launch_bounds__(256) void cvt_xw(const float* __restrict__ x,
                                              unsigned short* __restrict__ xb,
                                              const float* __restrict__ w,
                                              unsigned short* __restrict__ wt){
  __shared__ unsigned short tile[64][65];
  if(blockIdx.x < 2048){
    int i = (blockIdx.x * 256 + threadIdx.x) * 8;
    int stride = 2048 * 256 * 8;
    int n = M_ * K_;
    for(; i < n; i += stride){
      float4 v0 = *(const float4*)(x + i);
      float4 v1 = *(const float4*)(x + i + 4);
      u16x8 o;
      o[0]=f2bf(v0.x); o[1]=f2bf(v0.y); o[2]=f2bf(v0.z); o[3]=f2bf(v0.w);
      o[4]=f2bf(v1.x); o[5]=f2bf(v1.y); o[6]=f2bf(v1.z); o[7]=f2bf(v1.w);
      *(u16x8*)(xb + i) = o;
    }
  } else {
    int blk = blockIdx.x - 2048;
    int kt = (blk & 15) * 64, nt = (blk >> 4) * 64;
    int t = threadIdx.x, tn = t & 63, tk4 = t >> 6;
    #pragma unroll
    for(int r = 0; r < 16; ++r){
      int kl = r * 4 + tk4;
      tile[tn][kl] = f2bf(w[(kt + kl) * N_ + nt + tn]);
    }
    __syncthreads();
    #pragma unroll
    for(int r = 0; r < 16; ++r){
      int nl = r * 4 + tk4;
      int n  = nt + nl;
      int np = (n & ~127) | ((n & 1) << 6) | ((n >> 1) & 63);
      wt[(size_t)np * K_ + kt + tn] = tile[nl][tn];
    }
  }
}

// ---- K2: 256x256 8-phase GEMM (bf16 MFMA) + silu + v-store + s = q.k ---
// A-locality swizzle: XCD j (ids ≡ j mod 8) gets bx ∈ [16j,16j+16), all by.
// At the m248 template ceiling for K=1024 (848 TF) — do not touch.
__global__ __launch_bounds__(512, 2) void gemm8(
    const unsigned short* __restrict__ xb,   // [M][K]
    const unsigned short* __restrict__ wt,   // [N'][K]
    const float*  __restrict__ q,            // [H][D]
    unsigned short* __restrict__ vout,       // [B][H][T][D]
    float* __restrict__ s)                   // [M][H]
{
  __shared__ __align__(16) char lds[131072];

  const int t = threadIdx.x, lane = t & 63, wid = t >> 6;
  const int wr = wid >> 2, wc = wid & 3;          // 2M x 4N waves
  const int l15 = lane & 15, l4 = lane >> 4;

  const int id  = blockIdx.y * gridDim.x + blockIdx.x;
  const int by = (id >> 3) & 7;
  const int bx = (id & 7) * 16 + (id >> 6);
  const int brow = bx * 256, bcol = by * 256;

  f32x4 acc[8][4] = {};
  bf16x8 af[8], b0[4], b1[4];

  const int swl   = l15 & 7;
  const int aoff0 = l15 * 128 + (((0 + l4) ^ swl) << 4);
  const int aoff1 = l15 * 128 + (((4 + l4) ^ swl) << 4);

  auto stage = [&](int buf, int op, int half, const unsigned short* src,
                   int rowbase, int kt){
    char* base = lds + buf * 65536 + op * 32768 + half * 16384;
    #pragma unroll
    for(int L = 0; L < 2; ++L){
      int idx = L * 512 + t;
      int r = idx >> 3, ss = idx & 7;
      gload16(src + (size_t)(rowbase + half * 128 + r) * K_
                  + kt * 64 + ((ss ^ (r & 7)) << 3),
              base + idx * 16);
    }
  };
  auto rdA = [&](int buf, int miBase){
    const char* base = lds + buf * 65536 + wr * 16384;
    #pragma unroll
    for(int m = 0; m < 4; ++m){
      af[m*2+0] = *(const bf16x8*)(base + (miBase + m) * 2048 + aoff0);
      af[m*2+1] = *(const bf16x8*)(base + (miBase + m) * 2048 + aoff1);
    }
  };
  auto rdB = [&](int buf, int niBase, bf16x8 (&dst)[4]){
    const char* base = lds + buf * 65536 + 32768 + (wc >> 1) * 16384 + (wc & 1) * 8192;
    #pragma unroll
    for(int n = 0; n < 2; ++n){
      dst[n*2+0] = *(const bf16x8*)(base + (niBase + n) * 2048 + aoff0);
      dst[n*2+1] = *(const bf16x8*)(base + (niBase + n) * 2048 + aoff1);
    }
  };
  auto mmaq = [&](int miBase, bf16x8 (&bb)[4], int niBase){
    __builtin_amdgcn_s_setprio(1);
    #pragma unroll
    for(int m = 0; m < 4; ++m)
      #pragma unroll
      for(int n = 0; n < 2; ++n)
        #pragma unroll
        for(int k = 0; k < 2; ++k)
          acc[miBase+m][niBase+n] = __builtin_amdgcn_mfma_f32_16x16x32_bf16(
              af[m*2+k], bb[n*2+k], acc[miBase+m][niBase+n], 0, 0, 0);
    __builtin_amdgcn_s_setprio(0);
  };

  stage(0,0,0, xb, brow, 0); stage(0,0,1, xb, brow, 0);
  stage(0,1,0, wt, bcol, 0); stage(0,1,1, wt, bcol, 0);
  stage(1,1,0, wt, bcol, 1); stage(1,1,1, wt, bcol, 1);
  VM4(); BAR();

  for(int i = 0; i < 7; ++i){
    const int t1 = 2*i + 1;
    const int t2 = 2*i + 2;
    const int t3 = 2*i + 3;
    rdA(0,0); rdB(0,0,b0); stage(1,0,0, xb, brow, t1);
    BAR(); LGKM0(); mmaq(0,b0,0); BAR();
    rdB(0,2,b1); stage(1,0,1, xb, brow, t1);
    BAR(); LGKM0(); mmaq(0,b1,2); BAR();
    rdA(0,4); stage(0,1,0, wt, bcol, t2);
    BAR(); LGKM0(); mmaq(4,b1,2); BAR();
    stage(0,1,1, wt, bcol, t2); VM4();
    BAR(); mmaq(4,b0,0); BAR();
    rdA(1,0); rdB(1,0,b0); stage(0,0,0, xb, brow, t2);
    BAR(); LGKM0(); mmaq(0,b0,0); BAR();
    rdB(1,2,b1); stage(0,0,1, xb, brow, t2);
    BAR(); LGKM0(); mmaq(0,b1,2); BAR();
    rdA(1,4); stage(1,1,0, wt, bcol, t3);
    BAR(); LGKM0(); mmaq(4,b1,2); BAR();
    stage(1,1,1, wt, bcol, t3); VM4();
    BAR(); mmaq(4,b0,0); BAR();
  }
  // peeled i=7: tiles 14 (buf0) and 15 (buf1); stage only A-tile15.
  rdA(0,0); rdB(0,0,b0); stage(1,0,0, xb, brow, 15);
  BAR(); LGKM0(); mmaq(0,b0,0); BAR();
  rdB(0,2,b1); stage(1,0,1, xb, brow, 15);
  BAR(); LGKM0(); mmaq(0,b1,2); BAR();
  rdA(0,4);
  BAR(); LGKM0(); mmaq(4,b1,2); BAR();
  VM0();
  BAR(); mmaq(4,b0,0); BAR();
  rdA(1,0); rdB(1,0,b0);
  BAR(); LGKM0(); mmaq(0,b0,0); BAR();
  rdB(1,2,b1);
  BAR(); LGKM0(); mmaq(0,b1,2); BAR();
  rdA(1,4);
  BAR(); LGKM0(); mmaq(4,b1,2); BAR();
  mmaq(4,b0,0);

  const int hh = by * 2 + (wc >> 1);
  if(wc & 1){
    #pragma unroll
    for(int mi = 0; mi < 8; ++mi)
      #pragma unroll
      for(int r = 0; r < 4; ++r){
        const int gm = brow + wr*128 + mi*16 + l4*4 + r;
        const int bb = gm >> 10, tt = gm & (T_-1);
        unsigned short* vrow = vout + (((size_t)bb*H_ + hh)*T_ + tt)*D_;
        #pragma unroll
        for(int ni = 0; ni < 4; ++ni)
          vrow[ni*16 + l15] = f2bf(silu(acc[mi][ni][r]));
      }
  } else {
    float qv[4];
    #pragma unroll
    for(int ni = 0; ni < 4; ++ni) qv[ni] = q[hh*D_ + ni*16 + l15];
    #pragma unroll
    for(int mi = 0; mi < 8; ++mi)
      #pragma unroll
      for(int r = 0; r < 4; ++r){
        float sc = 0.f;
        #pragma unroll
        for(int ni = 0; ni < 4; ++ni) sc += qv[ni] * silu(acc[mi][ni][r]);
        sc += __shfl_xor(sc, 1); sc += __shfl_xor(sc, 2);
        sc += __shfl_xor(sc, 4); sc += __shfl_xor(sc, 8);
        if(l15 == 0){
          const int gm = brow + wr*128 + mi*16 + l4*4 + r;
          s[(size_t)gm * H_ + hh] = sc;
        }
      }
  }
}

// ---- K3: chunk summaries, FIXED chunk max (branch-free reduction) ------
__global__ __launch_bounds__(256) void scan1(
    const unsigned short* __restrict__ v, const float* __restrict__ s,
    float* __restrict__ snum, float* __restrict__ sden, float* __restrict__ smax)
{
  __shared__ float sst[CLEN][H_+1];
  const int blk = blockIdx.x;
  const int c = blk & (CHUNKS-1), b = blk / CHUNKS;
  const int t = threadIdx.x, lane = t & 63, w = t >> 6, h0 = w * 4;

  const float* sbase = s + ((size_t)b*T_ + c*CLEN) * H_;
  for(int i = t; i < CLEN*H_; i += 256) sst[i >> 4][i & 15] = sbase[i];
  __syncthreads();

  float mfix[4];
  #pragma unroll
  for(int j = 0; j < 4; ++j){
    float mm = sst[lane][h0 + j];
    mm = fmaxf(mm, __shfl_xor(mm, 1));  mm = fmaxf(mm, __shfl_xor(mm, 2));
    mm = fmaxf(mm, __shfl_xor(mm, 4));  mm = fmaxf(mm, __shfl_xor(mm, 8));
    mm = fmaxf(mm, __shfl_xor(mm, 16)); mm = fmaxf(mm, __shfl_xor(mm, 32));
    mfix[j] = mm;
  }

  float den[4] = {0.f,0.f,0.f,0.f}, num[4] = {0.f,0.f,0.f,0.f};
  const unsigned short* vb = v + (((size_t)b*H_ + h0)*T_ + c*CLEN)*D_;
  for(int tt = 0; tt < CLEN; ++tt){
    #pragma unroll
    for(int j = 0; j < 4; ++j){
      float p  = __expf(sst[tt][h0 + j] - mfix[j]);   // off-chain
      float vt = bf2f(vb[(size_t)j*T_*D_ + tt*D_ + lane]);
      den[j] += p;
      num[j] += p * vt;
    }
  }
  #pragma unroll
  for(int j = 0; j < 4; ++j){
    int sb = (b*H_ + h0 + j)*CHUNKS + c;
    snum[(size_t)sb*64 + lane] = num[j];
    if(lane == 0){ sden[sb] = den[j]; smax[sb] = mfix[j]; }
  }
}

// ---- K4: prefix combine + FIXED-max in-chunk prefix + head-sum -> out --
// oacc is 2-slot (34.8 KB): waves 0/1 write, waves 2/3 add -> 4 blocks/CU.
__global__ __launch_bounds__(256) void scan2h(
    const unsigned short* __restrict__ v, const float* __restrict__ s,
    const float* __restrict__ snum, const float* __restrict__ sden,
    const float* __restrict__ smax, float* __restrict__ out)
{
  __shared__ float sst[CLEN][H_+1];       // 4.25 KB
  __shared__ float oacc[2][CLEN][68];     // 34.8 KB
  const int blk = blockIdx.x;
  const int c = blk & (CHUNKS-1), b = blk / CHUNKS;
  const int t = threadIdx.x, lane = t & 63, w = t >> 6, h0 = w * 4;

  const float* sbase = s + ((size_t)b*T_ + c*CLEN) * H_;
  for(int i = t; i < CLEN*H_; i += 256) sst[i >> 4][i & 15] = sbase[i];
  __syncthreads();

  float num[4], den[4], m[4];
  #pragma unroll
  for(int j = 0; j < 4; ++j){ num[j] = 0.f; den[j] = 0.f; m[j] = -3.0e38f; }

  for(int cc = 0; cc < c; ++cc){           // exact prefix combine
    #pragma unroll
    for(int j = 0; j < 4; ++j){
      int sb = (b*H_ + h0 + j)*CHUNKS + cc;
      float m2 = smax[sb], d2 = sden[sb], n2 = snum[(size_t)sb*64 + lane];
      float cm = fmaxf(m[j], m2);
      float e1 = __expf(m[j]-cm), e2 = __expf(m2-cm);
      den[j] = den[j]*e1 + d2*e2;
      num[j] = num[j]*e1 + n2*e2;
      m[j] = cm;
    }
  }

  // rebase carry onto this chunk's fixed max
  float mfix[4];
  #pragma unroll
  for(int j = 0; j < 4; ++j){
    int sb = (b*H_ + h0 + j)*CHUNKS + c;
    mfix[j] = fmaxf(m[j], smax[sb]);
    float sc = __expf(m[j] - mfix[j]);
    den[j] *= sc;
    num[j] *= sc;
  }

  // local per-wave o for each tt, staged in registers (CLEN iterations)
  const unsigned short* vb = v + (((size_t)b*H_ + h0)*T_ + c*CLEN)*D_;
  // pass over time; waves 0/1 write slot w, waves 2/3 hold in oloc then add
  float oloc[CLEN];
  for(int tt = 0; tt < CLEN; ++tt){
    float o = 0.f;
    #pragma unroll
    for(int j = 0; j < 4; ++j){
      float p  = __expf(sst[tt][h0 + j] - mfix[j]);   // off-chain
      float vt = bf2f(vb[(size_t)j*T_*D_ + tt*D_ + lane]);
      den[j] += p;                                     // 2-cyc chain
      num[j] += p * vt;                                // 4-cyc chain
      o += num[j] * frcp(den[j]);                      // off-chain, fast rcp
    }
    if(w < 2) oacc[w][tt][lane] = o;
    else      oloc[tt] = o;
  }
  __syncthreads();
  if(w >= 2){
    for(int tt = 0; tt < CLEN; ++tt)
      oacc[w-2][tt][lane] += oloc[tt];
  }
  __syncthreads();

  {
    int tt = t >> 2, db = (t & 3) * 16;   // 64 tt x 4 d-groups of 16
    float* ob = out + ((size_t)b*T_ + c*CLEN + tt) * D_ + db;
    #pragma unroll
    for(int qd = 0; qd < 4; ++qd){
      f32x4 a0 = *(const f32x4*)&oacc[0][tt][db + qd*4];
      f32x4 a1 = *(const f32x4*)&oacc[1][tt][db + qd*4];
      *(f32x4*)(ob + qd*4) = a0 + a1;
    }
  }
}

extern "C" void kernel_launch(void* const* d_in, const int* in_sizes, int n_in,
                              void* d_out, int out_size, void* d_ws, size_t ws_size,
                              hipStream_t stream){
  (void)in_sizes; (void)n_in; (void)out_size; (void)ws_size;
  const float* x = (const float*)d_in[0];
  const float* w = (const float*)d_in[1];
  const float* q = (const float*)d_in[2];
  float* out = (float*)d_out;
  char* ws = (char*)d_ws;

  // ws: wt [0,4M); xb [4M,68M) — summaries alias dead xb after gemm
  //   (written by scan1, post-gemm): snum at 8M, sden 12M, smax 12M+64K.
  // vbuf [68M,132M); s [132M,134M).
  unsigned short* wt   = (unsigned short*)(ws);
  unsigned short* xb   = (unsigned short*)(ws + (4u  << 20));
  unsigned short* vbuf = (unsigned short*)(ws + (68u << 20));
  float* s    = (float*)(ws + (132u << 20));
  float* snum = (float*)(ws + (8u  << 20));
  float* sden = (float*)(ws + (12u << 20));
  float* smax = (float*)(ws + (12u << 20) + (1u << 16));

  cvt_xw<<<2048 + 512, 256, 0, stream>>>(x, xb, w, wt);
  gemm8<<<dim3(M_/256, N_/256), 512, 0, stream>>>(xb, wt, q, vbuf, s);
  scan1<<<B_*CHUNKS, 256, 0, stream>>>(vbuf, s, snum, sden, smax);
  scan2h<<<B_*CHUNKS, 256, 0, stream>>>(vbuf, s, snum, sden, smax, out);
}

// Round 13
// 231.798 us; speedup vs baseline: 1.0702x; 1.0702x over previous
//
#include <hip/hip_runtime.h>
#include <hip/hip_bf16.h>

#define B_ 32
#define T_ 1024
#define H_ 16
#define D_ 64
#define M_ (B_*T_)      // 32768 rows
#define N_ (H_*D_*2)    // 2048 cols
#define K_ 1024
#define CHUNKS 16
#define CLEN (T_/CHUNKS)   // 64

typedef __bf16 bf16x8 __attribute__((ext_vector_type(8)));
typedef float  f32x4  __attribute__((ext_vector_type(4)));
typedef unsigned short u16x8 __attribute__((ext_vector_type(8)));

__device__ __forceinline__ float bf2f(unsigned short u){
  union{ float f; unsigned int i; } c; c.i = ((unsigned int)u) << 16; return c.f;
}
__device__ __forceinline__ unsigned short f2bf(float f){
  union{ float f; unsigned int i; } c; c.f = f;
  unsigned int r = (c.i + 0x7FFFu + ((c.i >> 16) & 1u)) >> 16;   // RNE
  return (unsigned short)r;
}
__device__ __forceinline__ float silu(float x){ return x / (1.0f + __expf(-x)); }
__device__ __forceinline__ float frcp(float x){
  float r; asm("v_rcp_f32 %0, %1" : "=v"(r) : "v"(x)); return r;
}

__device__ __forceinline__ void gload16(const void* g, void* l){
  __builtin_amdgcn_global_load_lds(
      (const __attribute__((address_space(1))) void*)g,
      (__attribute__((address_space(3))) void*)l, 16, 0, 0);
}

#define BAR()   __builtin_amdgcn_s_barrier()
#define LGKM0() asm volatile("s_waitcnt lgkmcnt(0)" ::: "memory")
#define VM4()   asm volatile("s_waitcnt vmcnt(4)" ::: "memory")
#define VM0()   asm volatile("s_waitcnt vmcnt(0)" ::: "memory")

// ---- K0: fused x->bf16 (blocks 0..2047) + W transpose (blocks 2048+) ---
__global__ __launch_bounds__(256) void cvt_xw(const float* __restrict__ x,
                                              unsigned short* __restrict__ xb,
                                              const float* __restrict__ w,
                                              unsigned short* __restrict__ wt){
  __shared__ unsigned short tile[64][65];
  if(blockIdx.x < 2048){
    int i = (blockIdx.x * 256 + threadIdx.x) * 8;
    int stride = 2048 * 256 * 8;
    int n = M_ * K_;
    for(; i < n; i += stride){
      float4 v0 = *(const float4*)(x + i);
      float4 v1 = *(const float4*)(x + i + 4);
      u16x8 o;
      o[0]=f2bf(v0.x); o[1]=f2bf(v0.y); o[2]=f2bf(v0.z); o[3]=f2bf(v0.w);
      o[4]=f2bf(v1.x); o[5]=f2bf(v1.y); o[6]=f2bf(v1.z); o[7]=f2bf(v1.w);
      *(u16x8*)(xb + i) = o;
    }
  } else {
    int blk = blockIdx.x - 2048;
    int kt = (blk & 15) * 64, nt = (blk >> 4) * 64;
    int t = threadIdx.x, tn = t & 63, tk4 = t >> 6;
    #pragma unroll
    for(int r = 0; r < 16; ++r){
      int kl = r * 4 + tk4;
      tile[tn][kl] = f2bf(w[(kt + kl) * N_ + nt + tn]);
    }
    __syncthreads();
    #pragma unroll
    for(int r = 0; r < 16; ++r){
      int nl = r * 4 + tk4;
      int n  = nt + nl;
      int np = (n & ~127) | ((n & 1) << 6) | ((n >> 1) & 63);
      wt[(size_t)np * K_ + kt + tn] = tile[nl][tn];
    }
  }
}

// ---- K2: 256x256 8-phase GEMM (bf16 MFMA) + silu + v-store + s = q.k ---
// A-locality swizzle: XCD j (ids ≡ j mod 8) gets bx ∈ [16j,16j+16), all by.
// At the m248 template ceiling for K=1024 (848 TF) — do not touch.
__global__ __launch_bounds__(512, 2) void gemm8(
    const unsigned short* __restrict__ xb,   // [M][K]
    const unsigned short* __restrict__ wt,   // [N'][K]
    const float*  __restrict__ q,            // [H][D]
    unsigned short* __restrict__ vout,       // [B][H][T][D]
    float* __restrict__ s)                   // [M][H]
{
  __shared__ __align__(16) char lds[131072];

  const int t = threadIdx.x, lane = t & 63, wid = t >> 6;
  const int wr = wid >> 2, wc = wid & 3;          // 2M x 4N waves
  const int l15 = lane & 15, l4 = lane >> 4;

  const int id  = blockIdx.y * gridDim.x + blockIdx.x;
  const int by = (id >> 3) & 7;
  const int bx = (id & 7) * 16 + (id >> 6);
  const int brow = bx * 256, bcol = by * 256;

  f32x4 acc[8][4] = {};
  bf16x8 af[8], b0[4], b1[4];

  const int swl   = l15 & 7;
  const int aoff0 = l15 * 128 + (((0 + l4) ^ swl) << 4);
  const int aoff1 = l15 * 128 + (((4 + l4) ^ swl) << 4);

  auto stage = [&](int buf, int op, int half, const unsigned short* src,
                   int rowbase, int kt){
    char* base = lds + buf * 65536 + op * 32768 + half * 16384;
    #pragma unroll
    for(int L = 0; L < 2; ++L){
      int idx = L * 512 + t;
      int r = idx >> 3, ss = idx & 7;
      gload16(src + (size_t)(rowbase + half * 128 + r) * K_
                  + kt * 64 + ((ss ^ (r & 7)) << 3),
              base + idx * 16);
    }
  };
  auto rdA = [&](int buf, int miBase){
    const char* base = lds + buf * 65536 + wr * 16384;
    #pragma unroll
    for(int m = 0; m < 4; ++m){
      af[m*2+0] = *(const bf16x8*)(base + (miBase + m) * 2048 + aoff0);
      af[m*2+1] = *(const bf16x8*)(base + (miBase + m) * 2048 + aoff1);
    }
  };
  auto rdB = [&](int buf, int niBase, bf16x8 (&dst)[4]){
    const char* base = lds + buf * 65536 + 32768 + (wc >> 1) * 16384 + (wc & 1) * 8192;
    #pragma unroll
    for(int n = 0; n < 2; ++n){
      dst[n*2+0] = *(const bf16x8*)(base + (niBase + n) * 2048 + aoff0);
      dst[n*2+1] = *(const bf16x8*)(base + (niBase + n) * 2048 + aoff1);
    }
  };
  auto mmaq = [&](int miBase, bf16x8 (&bb)[4], int niBase){
    __builtin_amdgcn_s_setprio(1);
    #pragma unroll
    for(int m = 0; m < 4; ++m)
      #pragma unroll
      for(int n = 0; n < 2; ++n)
        #pragma unroll
        for(int k = 0; k < 2; ++k)
          acc[miBase+m][niBase+n] = __builtin_amdgcn_mfma_f32_16x16x32_bf16(
              af[m*2+k], bb[n*2+k], acc[miBase+m][niBase+n], 0, 0, 0);
    __builtin_amdgcn_s_setprio(0);
  };

  stage(0,0,0, xb, brow, 0); stage(0,0,1, xb, brow, 0);
  stage(0,1,0, wt, bcol, 0); stage(0,1,1, wt, bcol, 0);
  stage(1,1,0, wt, bcol, 1); stage(1,1,1, wt, bcol, 1);
  VM4(); BAR();

  for(int i = 0; i < 7; ++i){
    const int t1 = 2*i + 1;
    const int t2 = 2*i + 2;
    const int t3 = 2*i + 3;
    rdA(0,0); rdB(0,0,b0); stage(1,0,0, xb, brow, t1);
    BAR(); LGKM0(); mmaq(0,b0,0); BAR();
    rdB(0,2,b1); stage(1,0,1, xb, brow, t1);
    BAR(); LGKM0(); mmaq(0,b1,2); BAR();
    rdA(0,4); stage(0,1,0, wt, bcol, t2);
    BAR(); LGKM0(); mmaq(4,b1,2); BAR();
    stage(0,1,1, wt, bcol, t2); VM4();
    BAR(); mmaq(4,b0,0); BAR();
    rdA(1,0); rdB(1,0,b0); stage(0,0,0, xb, brow, t2);
    BAR(); LGKM0(); mmaq(0,b0,0); BAR();
    rdB(1,2,b1); stage(0,0,1, xb, brow, t2);
    BAR(); LGKM0(); mmaq(0,b1,2); BAR();
    rdA(1,4); stage(1,1,0, wt, bcol, t3);
    BAR(); LGKM0(); mmaq(4,b1,2); BAR();
    stage(1,1,1, wt, bcol, t3); VM4();
    BAR(); mmaq(4,b0,0); BAR();
  }
  // peeled i=7: tiles 14 (buf0) and 15 (buf1); stage only A-tile15.
  rdA(0,0); rdB(0,0,b0); stage(1,0,0, xb, brow, 15);
  BAR(); LGKM0(); mmaq(0,b0,0); BAR();
  rdB(0,2,b1); stage(1,0,1, xb, brow, 15);
  BAR(); LGKM0(); mmaq(0,b1,2); BAR();
  rdA(0,4);
  BAR(); LGKM0(); mmaq(4,b1,2); BAR();
  VM0();
  BAR(); mmaq(4,b0,0); BAR();
  rdA(1,0); rdB(1,0,b0);
  BAR(); LGKM0(); mmaq(0,b0,0); BAR();
  rdB(1,2,b1);
  BAR(); LGKM0(); mmaq(0,b1,2); BAR();
  rdA(1,4);
  BAR(); LGKM0(); mmaq(4,b1,2); BAR();
  mmaq(4,b0,0);

  const int hh = by * 2 + (wc >> 1);
  if(wc & 1){
    #pragma unroll
    for(int mi = 0; mi < 8; ++mi)
      #pragma unroll
      for(int r = 0; r < 4; ++r){
        const int gm = brow + wr*128 + mi*16 + l4*4 + r;
        const int bb = gm >> 10, tt = gm & (T_-1);
        unsigned short* vrow = vout + (((size_t)bb*H_ + hh)*T_ + tt)*D_;
        #pragma unroll
        for(int ni = 0; ni < 4; ++ni)
          vrow[ni*16 + l15] = f2bf(silu(acc[mi][ni][r]));
      }
  } else {
    float qv[4];
    #pragma unroll
    for(int ni = 0; ni < 4; ++ni) qv[ni] = q[hh*D_ + ni*16 + l15];
    #pragma unroll
    for(int mi = 0; mi < 8; ++mi)
      #pragma unroll
      for(int r = 0; r < 4; ++r){
        float sc = 0.f;
        #pragma unroll
        for(int ni = 0; ni < 4; ++ni) sc += qv[ni] * silu(acc[mi][ni][r]);
        sc += __shfl_xor(sc, 1); sc += __shfl_xor(sc, 2);
        sc += __shfl_xor(sc, 4); sc += __shfl_xor(sc, 8);
        if(l15 == 0){
          const int gm = brow + wr*128 + mi*16 + l4*4 + r;
          s[(size_t)gm * H_ + hh] = sc;
        }
      }
  }
}

// ---- K3: chunk summaries, FIXED chunk max (branch-free reduction) ------
__global__ __launch_bounds__(256) void scan1(
    const unsigned short* __restrict__ v, const float* __restrict__ s,
    float* __restrict__ snum, float* __restrict__ sden, float* __restrict__ smax)
{
  __shared__ float sst[CLEN][H_+1];
  const int blk = blockIdx.x;
  const int c = blk & (CHUNKS-1), b = blk / CHUNKS;
  const int t = threadIdx.x, lane = t & 63, w = t >> 6, h0 = w * 4;

  const float* sbase = s + ((size_t)b*T_ + c*CLEN) * H_;
  for(int i = t; i < CLEN*H_; i += 256) sst[i >> 4][i & 15] = sbase[i];
  __syncthreads();

  float mfix[4];
  #pragma unroll
  for(int j = 0; j < 4; ++j){
    float mm = sst[lane][h0 + j];
    mm = fmaxf(mm, __shfl_xor(mm, 1));  mm = fmaxf(mm, __shfl_xor(mm, 2));
    mm = fmaxf(mm, __shfl_xor(mm, 4));  mm = fmaxf(mm, __shfl_xor(mm, 8));
    mm = fmaxf(mm, __shfl_xor(mm, 16)); mm = fmaxf(mm, __shfl_xor(mm, 32));
    mfix[j] = mm;
  }

  float den[4] = {0.f,0.f,0.f,0.f}, num[4] = {0.f,0.f,0.f,0.f};
  const unsigned short* vb = v + (((size_t)b*H_ + h0)*T_ + c*CLEN)*D_;
  for(int tt = 0; tt < CLEN; ++tt){
    #pragma unroll
    for(int j = 0; j < 4; ++j){
      float p  = __expf(sst[tt][h0 + j] - mfix[j]);   // off-chain
      float vt = bf2f(vb[(size_t)j*T_*D_ + tt*D_ + lane]);
      den[j] += p;
      num[j] += p * vt;
    }
  }
  #pragma unroll
  for(int j = 0; j < 4; ++j){
    int sb = (b*H_ + h0 + j)*CHUNKS + c;
    snum[(size_t)sb*64 + lane] = num[j];
    if(lane == 0){ sden[sb] = den[j]; smax[sb] = mfix[j]; }
  }
}

// ---- K4: prefix combine + FIXED-max in-chunk prefix + head-sum -> out --
__global__ __launch_bounds__(256) void scan2h(
    const unsigned short* __restrict__ v, const float* __restrict__ s,
    const float* __restrict__ snum, const float* __restrict__ sden,
    const float* __restrict__ smax, float* __restrict__ out)
{
  __shared__ float sst[CLEN][H_+1];       // 4.25 KB
  __shared__ float oacc[4][CLEN][68];     // 68 KB padded
  const int blk = blockIdx.x;
  const int c = blk & (CHUNKS-1), b = blk / CHUNKS;
  const int t = threadIdx.x, lane = t & 63, w = t >> 6, h0 = w * 4;

  const float* sbase = s + ((size_t)b*T_ + c*CLEN) * H_;
  for(int i = t; i < CLEN*H_; i += 256) sst[i >> 4][i & 15] = sbase[i];
  __syncthreads();

  float num[4], den[4], m[4];
  #pragma unroll
  for(int j = 0; j < 4; ++j){ num[j] = 0.f; den[j] = 0.f; m[j] = -3.0e38f; }

  for(int cc = 0; cc < c; ++cc){           // exact prefix combine
    #pragma unroll
    for(int j = 0; j < 4; ++j){
      int sb = (b*H_ + h0 + j)*CHUNKS + cc;
      float m2 = smax[sb], d2 = sden[sb], n2 = snum[(size_t)sb*64 + lane];
      float cm = fmaxf(m[j], m2);
      float e1 = __expf(m[j]-cm), e2 = __expf(m2-cm);
      den[j] = den[j]*e1 + d2*e2;
      num[j] = num[j]*e1 + n2*e2;
      m[j] = cm;
    }
  }

  // rebase carry onto this chunk's fixed max
  float mfix[4];
  #pragma unroll
  for(int j = 0; j < 4; ++j){
    int sb = (b*H_ + h0 + j)*CHUNKS + c;
    mfix[j] = fmaxf(m[j], smax[sb]);
    float sc = __expf(m[j] - mfix[j]);
    den[j] *= sc;
    num[j] *= sc;
  }

  const unsigned short* vb = v + (((size_t)b*H_ + h0)*T_ + c*CLEN)*D_;
  for(int tt = 0; tt < CLEN; ++tt){
    float o = 0.f;
    #pragma unroll
    for(int j = 0; j < 4; ++j){
      float p  = __expf(sst[tt][h0 + j] - mfix[j]);   // off-chain
      float vt = bf2f(vb[(size_t)j*T_*D_ + tt*D_ + lane]);
      den[j] += p;                                     // 2-cyc chain
      num[j] += p * vt;                                // 4-cyc chain
      o += num[j] * frcp(den[j]);                      // off-chain, fast rcp
    }
    oacc[w][tt][lane] = o;
  }
  __syncthreads();

  {
    int tt = t >> 2, db = (t & 3) * 16;   // 64 tt x 4 d-groups of 16
    float* ob = out + ((size_t)b*T_ + c*CLEN + tt) * D_ + db;
    #pragma unroll
    for(int qd = 0; qd < 4; ++qd){
      f32x4 a0 = *(const f32x4*)&oacc[0][tt][db + qd*4];
      f32x4 a1 = *(const f32x4*)&oacc[1][tt][db + qd*4];
      f32x4 a2 = *(const f32x4*)&oacc[2][tt][db + qd*4];
      f32x4 a3 = *(const f32x4*)&oacc[3][tt][db + qd*4];
      f32x4 r = (a0 + a1) + (a2 + a3);
      *(f32x4*)(ob + qd*4) = r;
    }
  }
}

extern "C" void kernel_launch(void* const* d_in, const int* in_sizes, int n_in,
                              void* d_out, int out_size, void* d_ws, size_t ws_size,
                              hipStream_t stream){
  (void)in_sizes; (void)n_in; (void)out_size; (void)ws_size;
  const float* x = (const float*)d_in[0];
  const float* w = (const float*)d_in[1];
  const float* q = (const float*)d_in[2];
  float* out = (float*)d_out;
  char* ws = (char*)d_ws;

  // ws: wt [0,4M); xb [4M,68M) — summaries alias dead xb after gemm
  //   (written by scan1, post-gemm): snum at 8M, sden 12M, smax 12M+64K.
  // vbuf [68M,132M); s [132M,134M).
  unsigned short* wt   = (unsigned short*)(ws);
  unsigned short* xb   = (unsigned short*)(ws + (4u  << 20));
  unsigned short* vbuf = (unsigned short*)(ws + (68u << 20));
  float* s    = (float*)(ws + (132u << 20));
  float* snum = (float*)(ws + (8u  << 20));
  float* sden = (float*)(ws + (12u << 20));
  float* smax = (float*)(ws + (12u << 20) + (1u << 16));

  cvt_xw<<<2048 + 512, 256, 0, stream>>>(x, xb, w, wt);
  gemm8<<<dim3(M_/256, N_/256), 512, 0, stream>>>(xb, wt, q, vbuf, s);
  scan1<<<B_*CHUNKS, 256, 0, stream>>>(vbuf, s, snum, sden, smax);
  scan2h<<<B_*CHUNKS, 256, 0, stream>>>(vbuf, s, snum, sden, smax, out);
}